// Round 24
// baseline (8618.166 us; speedup 1.0000x reference)
//
#include <hip/hip_runtime.h>
#include <math.h>

#define D 256
#define SEQ 1000
#define NB 32
#define PATCH 160
#define NL 6
#define M_TOTAL (NB * SEQ)   // 32000
#define G3 (3 * D)           // 768
#define LDK 132              // padded u32 (k-pair) stride for MFMA staging

typedef _Float16 half8 __attribute__((ext_vector_type(8)));
typedef float f32x4 __attribute__((ext_vector_type(4)));

__device__ __forceinline__ float gelu_exact(float v) {
    return 0.5f * v * (1.0f + erff(v * 0.70710678118654752440f));
}

// Raw workgroup barrier: orders LDS (lgkmcnt) but does NOT drain vmcnt.
// (Harness-verified in rounds 3, 6, 7, 9, 12, 13, 16, 21, 23.)
__device__ __forceinline__ void bar_lds() {
    asm volatile("s_waitcnt lgkmcnt(0)" ::: "memory");
    __builtin_amdgcn_s_barrier();
    asm volatile("" ::: "memory");
}

// Fast sigmoid/tanh on native HW transcendentals (r21/r23-proven, passed).
__device__ __forceinline__ float fast_sigmoid(float g) {
    float e = __builtin_amdgcn_exp2f(-1.44269504f * g);
    return __builtin_amdgcn_rcpf(1.f + e);
}
__device__ __forceinline__ float fast_tanh(float a) {
    a = fminf(fmaxf(a, -12.f), 12.f);
    float t = __builtin_amdgcn_exp2f(2.88539008f * a);
    return (t - 1.f) * __builtin_amdgcn_rcpf(t + 1.f);
}

__device__ __forceinline__ unsigned int pk2(float a, float b) {
    unsigned short lo = __builtin_bit_cast(unsigned short, (_Float16)a);
    unsigned short hi = __builtin_bit_cast(unsigned short, (_Float16)b);
    return (unsigned int)lo | ((unsigned int)hi << 16);
}

// ---------------------------------------------------------------------------
// Kernel 1: conv patchify GEMM + exact GELU + pos_emb add
// ---------------------------------------------------------------------------
__global__ __launch_bounds__(256) void conv_gelu_pos(
    const float* __restrict__ wav, const float* __restrict__ cw,
    const float* __restrict__ pos, float* __restrict__ x)
{
    __shared__ float As[64][33];
    __shared__ float Bs[32][65];
    const int m0 = blockIdx.x * 64;
    const int n0 = blockIdx.y * 64;
    const int tid = threadIdx.x;
    const int tx = tid & 15;      // 0..15 -> n
    const int ty = tid >> 4;      // 0..15 -> m
    float acc[4][4] = {};

    for (int kc = 0; kc < PATCH; kc += 32) {
        for (int p = 0; p < 8; ++p) {
            int mr = p * 8 + (tid >> 5);
            int kk = tid & 31;
            int m = m0 + mr;
            int b = m / SEQ, s = m % SEQ;
            As[mr][kk] = wav[(size_t)b * 160000 + (size_t)s * PATCH + kc + kk];
        }
        for (int p = 0; p < 8; ++p) {
            int kr = p * 4 + (tid >> 6);
            int nn = tid & 63;
            Bs[kr][nn] = cw[(size_t)(kc + kr) * D + n0 + nn];
        }
        __syncthreads();
        #pragma unroll
        for (int kk = 0; kk < 32; ++kk) {
            float a[4], bb[4];
            #pragma unroll
            for (int i = 0; i < 4; ++i) a[i] = As[ty * 4 + i][kk];
            #pragma unroll
            for (int j = 0; j < 4; ++j) bb[j] = Bs[kk][tx * 4 + j];
            #pragma unroll
            for (int i = 0; i < 4; ++i)
                #pragma unroll
                for (int j = 0; j < 4; ++j)
                    acc[i][j] = fmaf(a[i], bb[j], acc[i][j]);
        }
        __syncthreads();
    }
    #pragma unroll
    for (int i = 0; i < 4; ++i) {
        int m = m0 + ty * 4 + i;
        int s = m % SEQ;
        int n = n0 + tx * 4;
        float4 v;
        v.x = gelu_exact(acc[i][0]) + pos[(size_t)s * D + n + 0];
        v.y = gelu_exact(acc[i][1]) + pos[(size_t)s * D + n + 1];
        v.z = gelu_exact(acc[i][2]) + pos[(size_t)s * D + n + 2];
        v.w = gelu_exact(acc[i][3]) + pos[(size_t)s * D + n + 3];
        *(float4*)&x[(size_t)m * D + n] = v;
    }
}

// ---------------------------------------------------------------------------
// Kernel 2: per-row mean / rstd (LayerNorm stats). One wave per row.
// ---------------------------------------------------------------------------
__global__ __launch_bounds__(64) void row_stats(
    const float* __restrict__ x, float* __restrict__ st)
{
    const int m = blockIdx.x;
    const int t = threadIdx.x;
    const float* r = x + (size_t)m * D;
    float s = 0.f, q = 0.f;
    #pragma unroll
    for (int i = 0; i < 4; ++i) {
        float v = r[t + 64 * i];
        s += v;
        q += v * v;
    }
    #pragma unroll
    for (int o = 32; o > 0; o >>= 1) {
        s += __shfl_down(s, o);
        q += __shfl_down(q, o);
    }
    if (t == 0) {
        float mu = s * (1.f / 256.f);
        float var = q * (1.f / 256.f) - mu * mu;
        st[2 * m]     = mu;
        st[2 * m + 1] = rsqrtf(var + 1e-5f);
    }
}

// ---------------------------------------------------------------------------
// Kernel 3: fused LN + input-projection GEMM on the MATRIX pipe (r23-proven,
// ~65us) with the staging bank conflicts fixed: thread q of a row handles
// pairs {2q,2q+1}+8i -> global float4 reads stay coalesced AND LDS writes
// hit banks {2q,2q+1} (distinct across q; cross-row 2-way alias free, m136).
// r23 counter: SQ_LDS_BANK_CONFLICT 2.2e7 from the old 32-pair-block layout.
// ---------------------------------------------------------------------------
__global__ __launch_bounds__(256) void ln_xp_mfma(
    const float* __restrict__ x, const float* __restrict__ st,
    const float* __restrict__ lnsc, const float* __restrict__ lnbi,
    const float* __restrict__ wih, const float* __restrict__ bih,
    float* __restrict__ xp)
{
    __shared__ unsigned int A16[64 * LDK];
    __shared__ unsigned int B16[64 * LDK];
    __shared__ float sc_s[D], bi_s[D];
    const int m0 = blockIdx.x * 64;
    const int n0 = blockIdx.y * 64;
    const int tid = threadIdx.x;
    const int w = tid >> 6, l = tid & 63;

    sc_s[tid] = lnsc[tid];
    bi_s[tid] = lnbi[tid];
    __syncthreads();

    // --- stage A (LN(x) -> fp16) and B (wih -> fp16): 4 thr/row ------------
    {
        const int r = tid >> 2;           // 0..63
        const int q = tid & 3;
        const int m = m0 + r;
        const float mu = st[2 * m], rs = st[2 * m + 1];
        const float* xr_ = x + (size_t)m * D;
        const float* wr_ = wih + (size_t)(n0 + r) * D;
        #pragma unroll
        for (int i = 0; i < 16; ++i) {
            const int pp = 2 * q + 8 * i;   // pair index (interleaved)
            const int k  = 2 * pp;
            float4 v = *(const float4*)(xr_ + k);
            A16[r * LDK + pp]     = pk2((v.x - mu) * rs * sc_s[k]     + bi_s[k],
                                        (v.y - mu) * rs * sc_s[k + 1] + bi_s[k + 1]);
            A16[r * LDK + pp + 1] = pk2((v.z - mu) * rs * sc_s[k + 2] + bi_s[k + 2],
                                        (v.w - mu) * rs * sc_s[k + 3] + bi_s[k + 3]);
            float4 u = *(const float4*)(wr_ + k);
            B16[r * LDK + pp]     = pk2(u.x, u.y);
            B16[r * LDK + pp + 1] = pk2(u.z, u.w);
        }
    }
    __syncthreads();

    // --- compute: wave w -> rows w*16..+15 ---------------------------------
    const int lr = l & 15, lg = l >> 4;
    uint4 afu[8];
    #pragma unroll
    for (int c = 0; c < 8; ++c)
        afu[c] = *(const uint4*)(A16 + (w * 16 + lr) * LDK + c * 16 + lg * 4);

    #pragma unroll
    for (int tile = 0; tile < 4; ++tile) {
        f32x4 acc = {0.f, 0.f, 0.f, 0.f};
        #pragma unroll
        for (int c = 0; c < 8; ++c) {
            uint4 bfu = *(const uint4*)(B16 + (tile * 16 + lr) * LDK + c * 16 + lg * 4);
            acc = __builtin_amdgcn_mfma_f32_16x16x32_f16(
                __builtin_bit_cast(half8, afu[c]),
                __builtin_bit_cast(half8, bfu), acc, 0, 0, 0);
        }
        const int col  = n0 + tile * 16 + lr;
        const int rowb = m0 + w * 16 + lg * 4;
        const float bb = bih[col];
        #pragma unroll
        for (int reg = 0; reg < 4; ++reg)
            xp[(size_t)(rowb + reg) * G3 + col] = acc[reg] + bb;
    }
}

// ---------------------------------------------------------------------------
// Kernel 4: pack w_hh fp32 -> fp16 MFMA B-fragments (r21/r23 version).
// Tile T covers whh rows 16T..16T+15 (row = gate*256+dout); chunk c, lane l,
// word j: k = 32c + 8*(l>>4) + 2j.
// ---------------------------------------------------------------------------
__global__ __launch_bounds__(256) void pack_whh(
    const float* __restrict__ whh, unsigned int* __restrict__ wfrag)
{
    const int idx = blockIdx.x * 256 + threadIdx.x;   // 0..98303
    const int j = idx & 3;
    const int l = (idx >> 2) & 63;
    const int c = (idx >> 8) & 7;
    const int t = idx >> 11;                          // 0..47
    const int n = t * 16 + (l & 15);
    const int k = c * 32 + (l >> 4) * 8 + 2 * j;
    wfrag[idx] = pk2(whh[(size_t)n * D + k], whh[(size_t)n * D + k + 1]);
}

// ---------------------------------------------------------------------------
// Kernel 5: GRU recurrence — wave-local gates, ONE barrier per step.
//
// r23 decomposition: step 2620cy = MFMA 1546 (hard floor: 384 MFMA / 4
// SIMDs x 16.1cy) + ~1070 overhead (2 barriers, gate_lds round trip,
// 4-wave-only gates). Root cause: wave w produced MFMA outputs for douts
// w*96..+95, but dout d's gates need r/z/n from THREE different waves.
// Fix: wave w now computes the r, z AND n tiles of ITS OWN 32 douts
// (tiles {2w,2w+1, 16+2w,16+2w+1, 32+2w,32+2w+1}; same pack, same 48
// MFMA/wave). Lanes 0..15 then hold all three gate values for douts
// 32w+l and 32w+16+l IN REGISTERS:
//   - gates run per-wave on all 8 waves in parallel (no gate_lds at all)
//   - h16 is parity double-buffered: gates write h16[(t+1)&1], A-frags
//     read h16[t&1] -> ONE end-of-step barrier suffices (it separates any
//     wave's next-step writes from laggards' current-step reads; buffers
//     at the same parity are 2 steps apart, fenced by 2 barriers).
// Gate math identical to r21/r23 (passed, absmax 4.9e-4).
// ---------------------------------------------------------------------------
__global__ __launch_bounds__(512, 1) void gru_scan_mfma(
    const float* __restrict__ xp, const unsigned int* __restrict__ wfrag,
    const float* __restrict__ bhh, float* __restrict__ x)
{
    __shared__ __align__(16) unsigned int h16[2][D / 2];   // parity buffers
    const int tid  = threadIdx.x;
    const int w    = tid >> 6;          // wave 0..7
    const int l    = tid & 63;          // lane
    const int batch = blockIdx.x;

    // --- resident weights: 6 tiles x 8 chunks = 192 u32/thread -------------
    // tile order: r(2w), r(2w+1), z(16+2w), z(16+2w+1), n(32+2w), n(32+2w+1)
    half8 bf[6][8];
    {
        const int T[6] = {2 * w, 2 * w + 1, 16 + 2 * w, 17 + 2 * w,
                          32 + 2 * w, 33 + 2 * w};
        #pragma unroll
        for (int i = 0; i < 6; ++i)
            #pragma unroll
            for (int c = 0; c < 8; ++c) {
                const uint4 v = *(const uint4*)(
                    wfrag + ((size_t)((T[i] * 8 + c) * 64 + l)) * 4);
                bf[i][c] = __builtin_bit_cast(half8, v);
            }
    }
    // --- per-lane douts (lanes 0..15): d0 = 32w+l, d1 = d0+16 --------------
    const int d0 = 32 * w + (l & 15);
    const int d1 = d0 + 16;
    float bh_r0 = 0.f, bh_r1 = 0.f, bh_z0 = 0.f, bh_z1 = 0.f,
          bh_n0 = 0.f, bh_n1 = 0.f;
    if (l < 16) {
        bh_r0 = bhh[d0];         bh_r1 = bhh[d1];
        bh_z0 = bhh[D + d0];     bh_z1 = bhh[D + d1];
        bh_n0 = bhh[2 * D + d0]; bh_n1 = bhh[2 * D + d1];
    }

    const float* xpb = xp + (size_t)batch * SEQ * G3;
    float* xb = x + (size_t)batch * SEQ * D;

    float h0 = 0.f, h1 = 0.f;           // fp32 h state for d0, d1
    if (tid < D / 2) h16[0][tid] = 0u;
    __syncthreads();

    const int lg = l >> 4;              // lane group 0..3
    for (int t = 0; t < SEQ; ++t) {
        const int par = t & 1;

        // early xp + residual loads (lanes 0..15); hide under MFMA
        float xr0 = 0.f, xz0 = 0.f, xn0 = 0.f, xo0 = 0.f;
        float xr1 = 0.f, xz1 = 0.f, xn1 = 0.f, xo1 = 0.f;
        if (l < 16) {
            const float* xpt = xpb + (size_t)t * G3;
            xr0 = xpt[d0]; xz0 = xpt[D + d0]; xn0 = xpt[2 * D + d0];
            xr1 = xpt[d1]; xz1 = xpt[D + d1]; xn1 = xpt[2 * D + d1];
            xo0 = xb[(size_t)t * D + d0];
            xo1 = xb[(size_t)t * D + d1];
        }

        // --- A fragments: h replicated across rows; broadcast LDS reads ----
        half8 af[8];
        #pragma unroll
        for (int c = 0; c < 8; ++c)
            af[c] = __builtin_bit_cast(half8,
                *(const uint4*)(h16[par] + 16 * c + 4 * lg));

        // --- MFMA: 6 tiles x 8 K-chunks; keep cf[0] (row 0) per tile -------
        float g0r, g1r, g0z, g1z, g0n, g1n;
        {
            f32x4 c0 = {0,0,0,0}, c1 = {0,0,0,0}, c2 = {0,0,0,0},
                  c3 = {0,0,0,0}, c4 = {0,0,0,0}, c5 = {0,0,0,0};
            #pragma unroll
            for (int c = 0; c < 8; ++c) {
                c0 = __builtin_amdgcn_mfma_f32_16x16x32_f16(af[c], bf[0][c], c0, 0, 0, 0);
                c1 = __builtin_amdgcn_mfma_f32_16x16x32_f16(af[c], bf[1][c], c1, 0, 0, 0);
                c2 = __builtin_amdgcn_mfma_f32_16x16x32_f16(af[c], bf[2][c], c2, 0, 0, 0);
                c3 = __builtin_amdgcn_mfma_f32_16x16x32_f16(af[c], bf[3][c], c3, 0, 0, 0);
                c4 = __builtin_amdgcn_mfma_f32_16x16x32_f16(af[c], bf[4][c], c4, 0, 0, 0);
                c5 = __builtin_amdgcn_mfma_f32_16x16x32_f16(af[c], bf[5][c], c5, 0, 0, 0);
            }
            g0r = c0[0]; g1r = c1[0]; g0z = c2[0];
            g1z = c3[0]; g0n = c4[0]; g1n = c5[0];
        }

        // --- gates: per-wave, lanes 0..15, all in registers ----------------
        if (l < 16) {
            float r0 = fast_sigmoid(xr0 + g0r + bh_r0);
            float r1 = fast_sigmoid(xr1 + g1r + bh_r1);
            float z0 = fast_sigmoid(xz0 + g0z + bh_z0);
            float z1 = fast_sigmoid(xz1 + g1z + bh_z1);
            float n0 = fast_tanh(xn0 + r0 * (g0n + bh_n0));
            float n1 = fast_tanh(xn1 + r1 * (g1n + bh_n1));
            float hn0 = (1.f - z0) * n0 + z0 * h0; h0 = hn0;
            float hn1 = (1.f - z1) * n1 + z1 * h1; h1 = hn1;
            // pack (d, d+1) pairs; neighbor value from adjacent lane
            float hn0n = __shfl_down(hn0, 1);
            float hn1n = __shfl_down(hn1, 1);
            if (!(l & 1)) {
                h16[1 - par][d0 >> 1] = pk2(hn0, hn0n);
                h16[1 - par][d1 >> 1] = pk2(hn1, hn1n);
            }
            xb[(size_t)t * D + d0] = xo0 + hn0;
            xb[(size_t)t * D + d1] = xo1 + hn1;
        }
        bar_lds();
    }
}

// ---------------------------------------------------------------------------
// Kernel 6: final LN + mean-pool over sequence
// ---------------------------------------------------------------------------
__global__ __launch_bounds__(256) void pool_ln(
    const float* __restrict__ x, const float* __restrict__ st,
    const float* __restrict__ fsc, const float* __restrict__ fbi,
    float* __restrict__ emb)
{
    const int b = blockIdx.x;
    const int d = threadIdx.x;
    float acc = 0.f;
    for (int s = 0; s < SEQ; ++s) {
        int m = b * SEQ + s;
        acc += (x[(size_t)m * D + d] - st[2 * m]) * st[2 * m + 1];
    }
    emb[b * D + d] = (acc * (1.f / (float)SEQ)) * fsc[d] + fbi[d];
}

// ---------------------------------------------------------------------------
// Kernel 7: classification head (tiny). Single block.
// ---------------------------------------------------------------------------
__global__ __launch_bounds__(256) void head_mlp(
    const float* __restrict__ emb, const float* __restrict__ w1,
    const float* __restrict__ b1, const float* __restrict__ w2,
    const float* __restrict__ b2, float* __restrict__ out)
{
    __shared__ float es[NB][D + 1];
    __shared__ float h1[NB][128 + 1];
    const int t = threadIdx.x;
    for (int i = t; i < NB * D; i += 256) es[i / D][i % D] = emb[i];
    __syncthreads();
    for (int i = t; i < NB * 128; i += 256) {
        int bb = i / 128, j = i % 128;
        float a = b1[j];
        for (int k = 0; k < D; ++k) a = fmaf(es[bb][k], w1[(size_t)k * 128 + j], a);
        h1[bb][j] = gelu_exact(a);
    }
    __syncthreads();
    for (int i = t; i < NB * 8; i += 256) {
        int bb = i / 8, c = i % 8;
        float a = b2[c];
        for (int k = 0; k < 128; ++k) a = fmaf(h1[bb][k], w2[(size_t)k * 8 + c], a);
        out[i] = a;
    }
}

// ---------------------------------------------------------------------------
extern "C" void kernel_launch(void* const* d_in, const int* in_sizes, int n_in,
                              void* d_out, int out_size, void* d_ws, size_t ws_size,
                              hipStream_t stream)
{
    const float* wav  = (const float*)d_in[0];
    const float* cw   = (const float*)d_in[1];
    const float* pos  = (const float*)d_in[2];
    const float* lnsc = (const float*)d_in[3];
    const float* lnbi = (const float*)d_in[4];
    const float* wih  = (const float*)d_in[5];
    const float* whh  = (const float*)d_in[6];
    const float* bih  = (const float*)d_in[7];
    const float* bhh  = (const float*)d_in[8];
    const float* fsc  = (const float*)d_in[9];
    const float* fbi  = (const float*)d_in[10];
    const float* hw1  = (const float*)d_in[11];
    const float* hb1  = (const float*)d_in[12];
    const float* hw2  = (const float*)d_in[13];
    const float* hb2  = (const float*)d_in[14];

    float* ws    = (float*)d_ws;
    float* x     = ws;                        // 8,192,000 f
    float* xp    = x + (size_t)M_TOTAL * D;   // 24,576,000 f
    float* st    = xp + (size_t)M_TOTAL * G3; // 64,000 f
    unsigned int* wfrag = (unsigned int*)(st + 2 * M_TOTAL); // 98,304 u32
    float* emb   = (float*)(wfrag + 98304);   // 8,192 f

    conv_gelu_pos<<<dim3(M_TOTAL / 64, D / 64), 256, 0, stream>>>(wav, cw, pos, x);

    for (int l = 0; l < NL; ++l) {
        row_stats<<<M_TOTAL, 64, 0, stream>>>(x, st);
        ln_xp_mfma<<<dim3(M_TOTAL / 64, G3 / 64), 256, 0, stream>>>(
            x, st, lnsc + (size_t)l * D, lnbi + (size_t)l * D,
            wih + (size_t)l * G3 * D, bih + (size_t)l * G3, xp);
        pack_whh<<<384, 256, 0, stream>>>(whh + (size_t)l * G3 * D, wfrag);
        gru_scan_mfma<<<NB, 512, 0, stream>>>(
            xp, wfrag, bhh + (size_t)l * G3, x);
    }

    row_stats<<<M_TOTAL, 64, 0, stream>>>(x, st);
    pool_ln<<<NB, D, 0, stream>>>(x, st, fsc, fbi, emb);
    head_mlp<<<1, 256, 0, stream>>>(emb, hw1, hb1, hw2, hb2, (float*)d_out);
}

// Round 25
// 7143.200 us; speedup vs baseline: 1.2065x; 1.2065x over previous
//
#include <hip/hip_runtime.h>
#include <math.h>

#define D 256
#define SEQ 1000
#define NB 32
#define PATCH 160
#define NL 6
#define M_TOTAL (NB * SEQ)   // 32000
#define G3 (3 * D)           // 768
#define LDK 132              // padded u32 (k-pair) stride for MFMA staging

typedef _Float16 half8 __attribute__((ext_vector_type(8)));
typedef float f32x4 __attribute__((ext_vector_type(4)));

__device__ __forceinline__ float gelu_exact(float v) {
    return 0.5f * v * (1.0f + erff(v * 0.70710678118654752440f));
}

// Raw workgroup barrier: orders LDS (lgkmcnt) but does NOT drain vmcnt.
// (Harness-verified in rounds 3, 6, 7, 9, 12, 13, 16, 21, 23.)
__device__ __forceinline__ void bar_lds() {
    asm volatile("s_waitcnt lgkmcnt(0)" ::: "memory");
    __builtin_amdgcn_s_barrier();
    asm volatile("" ::: "memory");
}

// Fast sigmoid/tanh on native HW transcendentals (r21/r23-proven, passed).
__device__ __forceinline__ float fast_sigmoid(float g) {
    float e = __builtin_amdgcn_exp2f(-1.44269504f * g);
    return __builtin_amdgcn_rcpf(1.f + e);
}
__device__ __forceinline__ float fast_tanh(float a) {
    a = fminf(fmaxf(a, -12.f), 12.f);
    float t = __builtin_amdgcn_exp2f(2.88539008f * a);
    return (t - 1.f) * __builtin_amdgcn_rcpf(t + 1.f);
}

__device__ __forceinline__ unsigned int pk2(float a, float b) {
    unsigned short lo = __builtin_bit_cast(unsigned short, (_Float16)a);
    unsigned short hi = __builtin_bit_cast(unsigned short, (_Float16)b);
    return (unsigned int)lo | ((unsigned int)hi << 16);
}

// ---------------------------------------------------------------------------
// Kernel 1: conv patchify GEMM + exact GELU + pos_emb add
// ---------------------------------------------------------------------------
__global__ __launch_bounds__(256) void conv_gelu_pos(
    const float* __restrict__ wav, const float* __restrict__ cw,
    const float* __restrict__ pos, float* __restrict__ x)
{
    __shared__ float As[64][33];
    __shared__ float Bs[32][65];
    const int m0 = blockIdx.x * 64;
    const int n0 = blockIdx.y * 64;
    const int tid = threadIdx.x;
    const int tx = tid & 15;      // 0..15 -> n
    const int ty = tid >> 4;      // 0..15 -> m
    float acc[4][4] = {};

    for (int kc = 0; kc < PATCH; kc += 32) {
        for (int p = 0; p < 8; ++p) {
            int mr = p * 8 + (tid >> 5);
            int kk = tid & 31;
            int m = m0 + mr;
            int b = m / SEQ, s = m % SEQ;
            As[mr][kk] = wav[(size_t)b * 160000 + (size_t)s * PATCH + kc + kk];
        }
        for (int p = 0; p < 8; ++p) {
            int kr = p * 4 + (tid >> 6);
            int nn = tid & 63;
            Bs[kr][nn] = cw[(size_t)(kc + kr) * D + n0 + nn];
        }
        __syncthreads();
        #pragma unroll
        for (int kk = 0; kk < 32; ++kk) {
            float a[4], bb[4];
            #pragma unroll
            for (int i = 0; i < 4; ++i) a[i] = As[ty * 4 + i][kk];
            #pragma unroll
            for (int j = 0; j < 4; ++j) bb[j] = Bs[kk][tx * 4 + j];
            #pragma unroll
            for (int i = 0; i < 4; ++i)
                #pragma unroll
                for (int j = 0; j < 4; ++j)
                    acc[i][j] = fmaf(a[i], bb[j], acc[i][j]);
        }
        __syncthreads();
    }
    #pragma unroll
    for (int i = 0; i < 4; ++i) {
        int m = m0 + ty * 4 + i;
        int s = m % SEQ;
        int n = n0 + tx * 4;
        float4 v;
        v.x = gelu_exact(acc[i][0]) + pos[(size_t)s * D + n + 0];
        v.y = gelu_exact(acc[i][1]) + pos[(size_t)s * D + n + 1];
        v.z = gelu_exact(acc[i][2]) + pos[(size_t)s * D + n + 2];
        v.w = gelu_exact(acc[i][3]) + pos[(size_t)s * D + n + 3];
        *(float4*)&x[(size_t)m * D + n] = v;
    }
}

// ---------------------------------------------------------------------------
// Kernel 2: per-row mean / rstd (LayerNorm stats). One wave per row.
// ---------------------------------------------------------------------------
__global__ __launch_bounds__(64) void row_stats(
    const float* __restrict__ x, float* __restrict__ st)
{
    const int m = blockIdx.x;
    const int t = threadIdx.x;
    const float* r = x + (size_t)m * D;
    float s = 0.f, q = 0.f;
    #pragma unroll
    for (int i = 0; i < 4; ++i) {
        float v = r[t + 64 * i];
        s += v;
        q += v * v;
    }
    #pragma unroll
    for (int o = 32; o > 0; o >>= 1) {
        s += __shfl_down(s, o);
        q += __shfl_down(q, o);
    }
    if (t == 0) {
        float mu = s * (1.f / 256.f);
        float var = q * (1.f / 256.f) - mu * mu;
        st[2 * m]     = mu;
        st[2 * m + 1] = rsqrtf(var + 1e-5f);
    }
}

// ---------------------------------------------------------------------------
// Kernel 3: fused LN + input-projection GEMM on the MATRIX pipe (r23-proven,
// ~65us) with the staging bank conflicts fixed (r24-verified: passed,
// absmax unchanged): thread q of a row handles pairs {2q,2q+1}+8i ->
// global float4 reads stay coalesced AND LDS writes hit banks {2q,2q+1}.
// ---------------------------------------------------------------------------
__global__ __launch_bounds__(256) void ln_xp_mfma(
    const float* __restrict__ x, const float* __restrict__ st,
    const float* __restrict__ lnsc, const float* __restrict__ lnbi,
    const float* __restrict__ wih, const float* __restrict__ bih,
    float* __restrict__ xp)
{
    __shared__ unsigned int A16[64 * LDK];
    __shared__ unsigned int B16[64 * LDK];
    __shared__ float sc_s[D], bi_s[D];
    const int m0 = blockIdx.x * 64;
    const int n0 = blockIdx.y * 64;
    const int tid = threadIdx.x;
    const int w = tid >> 6, l = tid & 63;

    sc_s[tid] = lnsc[tid];
    bi_s[tid] = lnbi[tid];
    __syncthreads();

    // --- stage A (LN(x) -> fp16) and B (wih -> fp16): 4 thr/row ------------
    {
        const int r = tid >> 2;           // 0..63
        const int q = tid & 3;
        const int m = m0 + r;
        const float mu = st[2 * m], rs = st[2 * m + 1];
        const float* xr_ = x + (size_t)m * D;
        const float* wr_ = wih + (size_t)(n0 + r) * D;
        #pragma unroll
        for (int i = 0; i < 16; ++i) {
            const int pp = 2 * q + 8 * i;   // pair index (interleaved)
            const int k  = 2 * pp;
            float4 v = *(const float4*)(xr_ + k);
            A16[r * LDK + pp]     = pk2((v.x - mu) * rs * sc_s[k]     + bi_s[k],
                                        (v.y - mu) * rs * sc_s[k + 1] + bi_s[k + 1]);
            A16[r * LDK + pp + 1] = pk2((v.z - mu) * rs * sc_s[k + 2] + bi_s[k + 2],
                                        (v.w - mu) * rs * sc_s[k + 3] + bi_s[k + 3]);
            float4 u = *(const float4*)(wr_ + k);
            B16[r * LDK + pp]     = pk2(u.x, u.y);
            B16[r * LDK + pp + 1] = pk2(u.z, u.w);
        }
    }
    __syncthreads();

    // --- compute: wave w -> rows w*16..+15 ---------------------------------
    const int lr = l & 15, lg = l >> 4;
    uint4 afu[8];
    #pragma unroll
    for (int c = 0; c < 8; ++c)
        afu[c] = *(const uint4*)(A16 + (w * 16 + lr) * LDK + c * 16 + lg * 4);

    #pragma unroll
    for (int tile = 0; tile < 4; ++tile) {
        f32x4 acc = {0.f, 0.f, 0.f, 0.f};
        #pragma unroll
        for (int c = 0; c < 8; ++c) {
            uint4 bfu = *(const uint4*)(B16 + (tile * 16 + lr) * LDK + c * 16 + lg * 4);
            acc = __builtin_amdgcn_mfma_f32_16x16x32_f16(
                __builtin_bit_cast(half8, afu[c]),
                __builtin_bit_cast(half8, bfu), acc, 0, 0, 0);
        }
        const int col  = n0 + tile * 16 + lr;
        const int rowb = m0 + w * 16 + lg * 4;
        const float bb = bih[col];
        #pragma unroll
        for (int reg = 0; reg < 4; ++reg)
            xp[(size_t)(rowb + reg) * G3 + col] = acc[reg] + bb;
    }
}

// ---------------------------------------------------------------------------
// Kernel 4: pack w_hh fp32 -> fp16 MFMA B-fragments (r21/r23 version).
// ---------------------------------------------------------------------------
__global__ __launch_bounds__(256) void pack_whh(
    const float* __restrict__ whh, unsigned int* __restrict__ wfrag)
{
    const int idx = blockIdx.x * 256 + threadIdx.x;   // 0..98303
    const int j = idx & 3;
    const int l = (idx >> 2) & 63;
    const int c = (idx >> 8) & 7;
    const int t = idx >> 11;                          // 0..47
    const int n = t * 16 + (l & 15);
    const int k = c * 32 + (l >> 4) * 8 + 2 * j;
    wfrag[idx] = pk2(whh[(size_t)n * D + k], whh[(size_t)n * D + k + 1]);
}

// ---------------------------------------------------------------------------
// Kernel 5: GRU recurrence — r23 version VERBATIM (best: 1.093 ms/dispatch,
// total 7.43 ms). r24's wave-local gates regressed (+23%): interleaving 6
// concurrent MFMA chains (24 live acc regs vs 4) + 16-active-lane gates
// degraded issue/coalescing more than the removed barrier saved. Both
// overhead-compression attempts (r22 hybrid, r24 wave-local) failed from
// independent directions -> this structure is the practical optimum.
// ---------------------------------------------------------------------------
__global__ __launch_bounds__(512, 1) void gru_scan_mfma(
    const float* __restrict__ xp, const unsigned int* __restrict__ wfrag,
    const float* __restrict__ bhh, float* __restrict__ x)
{
    __shared__ __align__(16) unsigned int h16_lds[D / 2];  // packed fp16 pairs
    __shared__ float gate_lds[G3];                         // W^T.h results
    const int tid  = threadIdx.x;
    const int w    = tid >> 6;          // wave 0..7
    const int l    = tid & 63;          // lane
    const int d    = tid;               // gate thread's output dim (tid<256)
    const int batch = blockIdx.x;

    // --- resident weights: 48 B-fragments = 192 u32/thread, coalesced ------
    half8 bf[6][8];
    {
        #pragma unroll
        for (int i = 0; i < 6; ++i)
            #pragma unroll
            for (int c = 0; c < 8; ++c) {
                const uint4 v = *(const uint4*)(
                    wfrag + ((size_t)(((w * 6 + i) * 8 + c) * 64 + l)) * 4);
                bf[i][c] = __builtin_bit_cast(half8, v);
            }
    }
    float bh_r = 0.f, bh_z = 0.f, bh_n = 0.f;
    if (tid < D) {
        bh_r = bhh[d];
        bh_z = bhh[D + d];
        bh_n = bhh[2 * D + d];
    }

    const float* xpb = xp + (size_t)batch * SEQ * G3;
    float* xb = x + (size_t)batch * SEQ * D;

    float hreg = 0.f;                   // fp32 h state, register-resident
    if (tid < D / 2) h16_lds[tid] = 0u;
    __syncthreads();

    const int lg = l >> 4;              // lane group 0..3
    for (int t = 0; t < SEQ; ++t) {
        // xp + residual loads early (tid<256); latency hides under MFMA
        float xr = 0.f, xz = 0.f, xn_ = 0.f, xold = 0.f;
        if (tid < D) {
            const float* xpt = xpb + (size_t)t * G3;
            xr   = xpt[d];
            xz   = xpt[D + d];
            xn_  = xpt[2 * D + d];
            xold = xb[(size_t)t * D + d];
        }

        // --- A fragments: h replicated across rows; broadcast LDS reads ----
        half8 af[8];
        #pragma unroll
        for (int c = 0; c < 8; ++c)
            af[c] = __builtin_bit_cast(half8,
                *(const uint4*)(h16_lds + 16 * c + 4 * lg));

        // --- MFMA phase: 6 tiles x 8 K-chunks, C accumulates K in-pipe -----
        #pragma unroll
        for (int i = 0; i < 6; ++i) {
            f32x4 cf = {0.f, 0.f, 0.f, 0.f};
            #pragma unroll
            for (int c = 0; c < 8; ++c)
                cf = __builtin_amdgcn_mfma_f32_16x16x32_f16(af[c], bf[i][c], cf, 0, 0, 0);
            if (l < 16) gate_lds[(w * 6 + i) * 16 + l] = cf[0];  // row 0
        }
        bar_lds();

        // --- gates (tid<256): native exp2/rcp, h in register ---------------
        if (tid < D) {
            float ar = gate_lds[d];
            float az = gate_lds[D + d];
            float an = gate_lds[2 * D + d];
            float r = fast_sigmoid(xr + ar + bh_r);
            float z = fast_sigmoid(xz + az + bh_z);
            float n = fast_tanh(xn_ + r * (an + bh_n));
            float hnew = (1.f - z) * n + z * hreg;
            hreg = hnew;
            // pack (h[d], h[d+1]) -> fp16 pair; neighbors are adjacent lanes
            float hn1 = __shfl_down(hnew, 1);
            if (!(d & 1)) {
                h16_lds[d >> 1] = pk2(hnew, hn1);
            }
            xb[(size_t)t * D + d] = xold + hnew;
        }
        bar_lds();
    }
}

// ---------------------------------------------------------------------------
// Kernel 6: final LN + mean-pool over sequence
// ---------------------------------------------------------------------------
__global__ __launch_bounds__(256) void pool_ln(
    const float* __restrict__ x, const float* __restrict__ st,
    const float* __restrict__ fsc, const float* __restrict__ fbi,
    float* __restrict__ emb)
{
    const int b = blockIdx.x;
    const int d = threadIdx.x;
    float acc = 0.f;
    for (int s = 0; s < SEQ; ++s) {
        int m = b * SEQ + s;
        acc += (x[(size_t)m * D + d] - st[2 * m]) * st[2 * m + 1];
    }
    emb[b * D + d] = (acc * (1.f / (float)SEQ)) * fsc[d] + fbi[d];
}

// ---------------------------------------------------------------------------
// Kernel 7: classification head (tiny). Single block.
// ---------------------------------------------------------------------------
__global__ __launch_bounds__(256) void head_mlp(
    const float* __restrict__ emb, const float* __restrict__ w1,
    const float* __restrict__ b1, const float* __restrict__ w2,
    const float* __restrict__ b2, float* __restrict__ out)
{
    __shared__ float es[NB][D + 1];
    __shared__ float h1[NB][128 + 1];
    const int t = threadIdx.x;
    for (int i = t; i < NB * D; i += 256) es[i / D][i % D] = emb[i];
    __syncthreads();
    for (int i = t; i < NB * 128; i += 256) {
        int bb = i / 128, j = i % 128;
        float a = b1[j];
        for (int k = 0; k < D; ++k) a = fmaf(es[bb][k], w1[(size_t)k * 128 + j], a);
        h1[bb][j] = gelu_exact(a);
    }
    __syncthreads();
    for (int i = t; i < NB * 8; i += 256) {
        int bb = i / 8, c = i % 8;
        float a = b2[c];
        for (int k = 0; k < 128; ++k) a = fmaf(h1[bb][k], w2[(size_t)k * 8 + c], a);
        out[i] = a;
    }
}

// ---------------------------------------------------------------------------
extern "C" void kernel_launch(void* const* d_in, const int* in_sizes, int n_in,
                              void* d_out, int out_size, void* d_ws, size_t ws_size,
                              hipStream_t stream)
{
    const float* wav  = (const float*)d_in[0];
    const float* cw   = (const float*)d_in[1];
    const float* pos  = (const float*)d_in[2];
    const float* lnsc = (const float*)d_in[3];
    const float* lnbi = (const float*)d_in[4];
    const float* wih  = (const float*)d_in[5];
    const float* whh  = (const float*)d_in[6];
    const float* bih  = (const float*)d_in[7];
    const float* bhh  = (const float*)d_in[8];
    const float* fsc  = (const float*)d_in[9];
    const float* fbi  = (const float*)d_in[10];
    const float* hw1  = (const float*)d_in[11];
    const float* hb1  = (const float*)d_in[12];
    const float* hw2  = (const float*)d_in[13];
    const float* hb2  = (const float*)d_in[14];

    float* ws    = (float*)d_ws;
    float* x     = ws;                        // 8,192,000 f
    float* xp    = x + (size_t)M_TOTAL * D;   // 24,576,000 f
    float* st    = xp + (size_t)M_TOTAL * G3; // 64,000 f
    unsigned int* wfrag = (unsigned int*)(st + 2 * M_TOTAL); // 98,304 u32
    float* emb   = (float*)(wfrag + 98304);   // 8,192 f

    conv_gelu_pos<<<dim3(M_TOTAL / 64, D / 64), 256, 0, stream>>>(wav, cw, pos, x);

    for (int l = 0; l < NL; ++l) {
        row_stats<<<M_TOTAL, 64, 0, stream>>>(x, st);
        ln_xp_mfma<<<dim3(M_TOTAL / 64, G3 / 64), 256, 0, stream>>>(
            x, st, lnsc + (size_t)l * D, lnbi + (size_t)l * D,
            wih + (size_t)l * G3 * D, bih + (size_t)l * G3, xp);
        pack_whh<<<384, 256, 0, stream>>>(whh + (size_t)l * G3 * D, wfrag);
        gru_scan_mfma<<<NB, 512, 0, stream>>>(
            xp, wfrag, bhh + (size_t)l * G3, x);
    }

    row_stats<<<M_TOTAL, 64, 0, stream>>>(x, st);
    pool_ln<<<NB, D, 0, stream>>>(x, st, fsc, fbi, emb);
    head_mlp<<<1, 256, 0, stream>>>(emb, hw1, hb1, hw2, hb2, (float*)d_out);
}